// Round 5
// baseline (90.467 us; speedup 1.0000x reference)
//
#include <hip/hip_runtime.h>

typedef unsigned long long u64;
typedef _Float16 f16x8 __attribute__((ext_vector_type(8)));
typedef float    f32x4 __attribute__((ext_vector_type(4)));
typedef __fp16   fp16x2 __attribute__((ext_vector_type(2)));

#define G_    4096
#define NPTS  16384

union H8 { _Float16 h[8]; uint4 u; };
union PK2 { fp16x2 h[2]; uint2 u; };
union PK4 { fp16x2 h[4]; uint4 u; };

#define MFMA_(A_,B_,C_) __builtin_amdgcn_mfma_f32_16x16x32_f16((A_),(B_),(C_),0,0,0)

// ---------------- ws layout (bytes) ----------------
// pc   i32 [16][16384]    @ 0        (1048576)
// w1f  f16 [16][2][64][8] @ 1048576  (32768)   A-frag order, K=64 (x channels only)
// w2f  f16 [16][8][64][8] @ 1081344  (131072)
// w3f  f16 [8][64][8]     @ 1212416  (8192)    rows 3..15 zero
// w1n  f32 [256][2]       @ 1220608  (2048)    W1 cols 64,65 (noise channels)
// total 1222656

// ---- merged prep: blocks 0..15 = sampling (per batch); blocks 16..58 = weight bake ----
__global__ __launch_bounds__(256) void kP(const float* __restrict__ dens,
                                          int* __restrict__ pc,
                                          const float* __restrict__ W1,
                                          const float* __restrict__ W2,
                                          const float* __restrict__ W3,
                                          _Float16* __restrict__ w1f,
                                          _Float16* __restrict__ w2f,
                                          _Float16* __restrict__ w3f,
                                          float* __restrict__ w1n){
  __shared__ double sred[256];
  __shared__ u64  keys[4096];     // 32 KB
  __shared__ int  nvs[4096];      // 16 KB
  __shared__ int  binidx[4096];   // 16 KB
  __shared__ int  hist[1024];
  __shared__ int  cab[1024];
  __shared__ int  scan[256];
  __shared__ float Sf;
  __shared__ int  remS, BstarS, needS, cntS;
  const int t = threadIdx.x;

  if (blockIdx.x >= 16){
    // ---------------- weight bake path ----------------
    const int e = (blockIdx.x - 16)*256 + t;   // 11008 entries
    H8 v;
    if (e < 8192){                                 // w2f: [RT 16][kt 8][lane 64]
      const int RT = e >> 9, kt = (e >> 6) & 7, l = e & 63;
      const int m = RT*16 + (l & 15), k = kt*32 + ((l >> 4) << 3);
      #pragma unroll
      for (int j = 0; j < 8; ++j) v.h[j] = (_Float16)W2[m*256 + k + j];
      *(uint4*)&w2f[e*8] = v.u;
    } else if (e < 10240){                         // w1f: [RT 16][kt 2][lane 64]
      const int e2 = e - 8192;
      const int RT = e2 >> 7, r2 = e2 & 127, kt = r2 >> 6, l = r2 & 63;
      const int m = RT*16 + (l & 15), k = kt*32 + ((l >> 4) << 3);   // k < 64
      #pragma unroll
      for (int j = 0; j < 8; ++j) v.h[j] = (_Float16)W1[m*66 + k + j];
      *(uint4*)&w1f[e2*8] = v.u;
    } else if (e < 10752){                         // w3f: [kt 8][lane 64]
      const int e3 = e - 10240;
      const int kt = e3 >> 6, l = e3 & 63;
      const int m = l & 15, k = kt*32 + ((l >> 4) << 3);
      #pragma unroll
      for (int j = 0; j < 8; ++j) v.h[j] = (m < 3) ? (_Float16)W3[m*256 + k + j] : (_Float16)0.f;
      *(uint4*)&w3f[e3*8] = v.u;
    } else if (e < 11008){                         // w1n: noise-channel cols
      const int r = e - 10752;
      w1n[r*2 + 0] = W1[r*66 + 64];
      w1n[r*2 + 1] = W1[r*66 + 65];
    }
    return;
  }

  // ---------------- sampling path (one block per batch) ----------------
  const int b = blockIdx.x;
  const float* d = dens + b*G_;

  for (int j = t; j < 1024; j += 256) hist[j] = 0;
  if (t == 0) cntS = 0;

  // exact same summation pattern as passing rounds: per-thread d[t+256j], tree over 256
  double s = 0.0;
  for (int j = 0; j < 16; ++j) s += (double)d[t + 256*j];
  sred[t] = s; __syncthreads();
  for (int off = 128; off > 0; off >>= 1){
    if (t < off) sred[t] += sred[t + off];
    __syncthreads();
  }
  if (t == 0) Sf = (float)sred[0];
  __syncthreads();
  const float S = Sf;

  int bi[16]; int bs = 0;
  #pragma unroll
  for (int j = 0; j < 16; ++j){
    const int i = t + 256*j;
    const float p  = d[i] / S;
    const float sc = p * 16384.0f;     // exact (x2^14)
    const float fl = floorf(sc);
    const float fr = sc - fl;          // exact
    bi[j] = (int)fl; bs += bi[j];
    const unsigned fb = __float_as_uint(fr);
    keys[i] = ((u64)fb << 12) | (u64)(4095 - i);
    atomicAdd(&hist[fb >> 20], 1);
  }
  scan[t] = bs; __syncthreads();
  for (int off = 128; off > 0; off >>= 1){
    if (t < off) scan[t] += scan[t + off];
    __syncthreads();
  }
  if (t == 0) remS = 16384 - scan[0];
  __syncthreads();
  const int rem = remS;

  // suffix-scan histogram (1024 bins, 4/thread) -> cab[q] = #keys in bins > q
  const int h0 = hist[4*t], h1 = hist[4*t+1], h2 = hist[4*t+2], h3 = hist[4*t+3];
  const int gs = h0 + h1 + h2 + h3;
  __syncthreads();
  scan[t] = gs; __syncthreads();
  for (int off = 1; off < 256; off <<= 1){
    const int v2 = (t + off < 256) ? scan[t + off] : 0;
    __syncthreads();
    scan[t] += v2;
    __syncthreads();
  }
  const int sAfter = scan[t] - gs;
  cab[4*t+3] = sAfter;
  cab[4*t+2] = sAfter + h3;
  cab[4*t+1] = sAfter + h3 + h2;
  cab[4*t+0] = sAfter + h3 + h2 + h1;
  if (t == 0){ BstarS = 0x7fffffff; needS = 0; }
  __syncthreads();
  if (rem > 0){
    const int ca[4] = {cab[4*t], cab[4*t+1], cab[4*t+2], cab[4*t+3]};
    const int hh[4] = {h0, h1, h2, h3};
    #pragma unroll
    for (int q = 0; q < 4; ++q)
      if (ca[q] < rem && rem <= ca[q] + hh[q]){ BstarS = 4*t + q; needS = rem - ca[q]; }
  }
  __syncthreads();
  const int Bstar = BstarS, need = needS;

  #pragma unroll
  for (int j = 0; j < 16; ++j){
    const int i = t + 256*j;
    const int bin = (int)(keys[i] >> 32);
    nvs[i] = bi[j] + ((bin > Bstar) ? 1 : 0);
    if (bin == Bstar){ const int pos = atomicAdd(&cntS, 1); binidx[pos] = i; }
  }
  __syncthreads();
  const int cnt = cntS;
  for (int p = t; p < cnt; p += 256){
    const u64 K = keys[binidx[p]];
    int r = 0;
    for (int q = 0; q < cnt; ++q) r += (keys[binidx[q]] > K) ? 1 : 0;
    if (r < need) nvs[binidx[p]] += 1;
  }
  __syncthreads();

  // prefix + expand (thread t owns cells t*16..t*16+15)
  int loc[16]; int ls = 0;
  #pragma unroll
  for (int j = 0; j < 16; ++j){ loc[j] = nvs[t*16 + j]; ls += loc[j]; }
  __syncthreads();
  scan[t] = ls; __syncthreads();
  for (int off = 1; off < 256; off <<= 1){
    const int v2 = (t >= off) ? scan[t - off] : 0;
    __syncthreads();
    scan[t] += v2;
    __syncthreads();
  }
  int off0 = scan[t] - ls;
  int* o = pc + b*NPTS;
  #pragma unroll
  for (int j = 0; j < 16; ++j){
    const int c = t*16 + j;
    for (int r = 0; r < loc[j]; ++r) o[off0++] = c;
  }
}

// ---- fused MLP via f16 MFMA: 64 points/block, 4 waves, wave = 64 rows x 64 pts ----
// reg budget: 64 acc + A-pipeline 32 + ~50 arch ~= 146 <= 170 -> 3 blocks/CU, no spill.
__global__ __launch_bounds__(256, 3) void kE(
    const float* __restrict__ x, const float* __restrict__ noise,
    const _Float16* __restrict__ w1f, const _Float16* __restrict__ w2f,
    const _Float16* __restrict__ w3f, const float* __restrict__ w1n,
    const float* __restrict__ b1, const float* __restrict__ b2, const float* __restrict__ b3,
    const int* __restrict__ pc, float* __restrict__ out)
{
  __shared__ _Float16 Hb[16384];   // 32KB; reused: Bin(8KB) -> Bh1(32KB) -> Bh2(32KB)
  __shared__ int   cells[64];
  __shared__ float rndS[2][64];
  const int b = blockIdx.y, p0 = blockIdx.x*64, tid = threadIdx.x;
  const int w = tid >> 6, lane = tid & 63;

  // ---- staging: direct per-thread pc load (no barrier dependency) ----
  const int pt_g  = tid >> 2;                        // gather point 0..63
  const int cell_g = pc[b*NPTS + p0 + pt_g];         // 4x redundant, cache-hit
  if (tid < 64) cells[tid] = pc[b*NPTS + p0 + tid];
  if (tid >= 64 && tid < 192){
    const int rr = (tid - 64) >> 6, p = tid & 63;
    rndS[rr][p] = noise[(b*2 + rr)*NPTS + p0 + p]*2.f - 1.f;
  }
  {
    const int koct = tid & 3;
    const int ct = pt_g >> 4, lane2 = (pt_g & 15) + koct*16;
    #pragma unroll
    for (int kt = 0; kt < 2; ++kt){
      const int kbase = kt*32 + koct*8;              // < 64 always
      const float* xb = x + ((size_t)(b*64 + kbase))*G_ + cell_g;
      float xv[8];
      #pragma unroll
      for (int j = 0; j < 8; ++j) xv[j] = xb[(size_t)j*G_];
      PK4 v;
      v.h[0] = __builtin_amdgcn_cvt_pkrtz(xv[0], xv[1]);
      v.h[1] = __builtin_amdgcn_cvt_pkrtz(xv[2], xv[3]);
      v.h[2] = __builtin_amdgcn_cvt_pkrtz(xv[4], xv[5]);
      v.h[3] = __builtin_amdgcn_cvt_pkrtz(xv[6], xv[7]);
      *(uint4*)&Hb[((kt*4 + ct)*64 + lane2)*8] = v.u;
    }
  }
  __syncthreads();

  f32x4 acc[4][4];
  const f32x4 zz = {0.f, 0.f, 0.f, 0.f};
  #pragma unroll
  for (int rt = 0; rt < 4; ++rt)
    #pragma unroll
    for (int ct = 0; ct < 4; ++ct) acc[rt][ct] = zz;

  const int wr = w*4;

  // -------- layer 1: K=64 (2 k-tiles, x channels only) --------
  __builtin_amdgcn_s_setprio(1);
  #pragma unroll
  for (int kt = 0; kt < 2; ++kt){
    f16x8 B[4];
    #pragma unroll
    for (int ct = 0; ct < 4; ++ct) B[ct] = *(f16x8*)&Hb[((kt*4 + ct)*64 + lane)*8];
    #pragma unroll
    for (int rt = 0; rt < 4; ++rt){
      f16x8 A = *(const f16x8*)&w1f[(((wr + rt)*2 + kt)*64 + lane)*8];
      #pragma unroll
      for (int ct = 0; ct < 4; ++ct)
        acc[rt][ct] = MFMA_(A, B[ct], acc[rt][ct]);
    }
  }
  __builtin_amdgcn_s_setprio(0);

  // ---- prefetch layer-2 A-frags for kt=0,1 (hide L2 latency under epilogue) ----
  f16x8 A0[4], A1[4];
  #pragma unroll
  for (int rt = 0; rt < 4; ++rt){
    A0[rt] = *(const f16x8*)&w2f[(((wr + rt)*8 + 0)*64 + lane)*8];
    A1[rt] = *(const f16x8*)&w2f[(((wr + rt)*8 + 1)*64 + lane)*8];
  }

  // ---- rank-2 noise update (f32): acc += w1[:,64] x rnd0 + w1[:,65] x rnd1 ----
  {
    const int m16 = lane & 15, khi = lane >> 4;
    float rn0[4], rn1[4];
    #pragma unroll
    for (int ct = 0; ct < 4; ++ct){
      rn0[ct] = rndS[0][ct*16 + m16];
      rn1[ct] = rndS[1][ct*16 + m16];
    }
    #pragma unroll
    for (int rt = 0; rt < 4; ++rt){
      const int row0 = w*64 + rt*16 + khi*4;
      const float4 wa = *(const float4*)&w1n[row0*2];       // rows row0,row0+1
      const float4 wb = *(const float4*)&w1n[row0*2 + 4];   // rows row0+2,row0+3
      #pragma unroll
      for (int ct = 0; ct < 4; ++ct){
        acc[rt][ct][0] += wa.x*rn0[ct] + wa.y*rn1[ct];
        acc[rt][ct][1] += wa.z*rn0[ct] + wa.w*rn1[ct];
        acc[rt][ct][2] += wb.x*rn0[ct] + wb.y*rn1[ct];
        acc[rt][ct][3] += wb.z*rn0[ct] + wb.w*rn1[ct];
      }
    }
  }
  __syncthreads();

  // -------- epilogue L1: bias+relu -> f16 fragment order (Bh1), pkrtz --------
  #pragma unroll
  for (int rt = 0; rt < 4; ++rt){
    const int row0 = w*64 + rt*16 + ((lane >> 4) << 2);
    const float4 bq = *(const float4*)&b1[row0];
    const int kt2 = row0 >> 5, c16 = (row0 >> 3) & 3, j0 = row0 & 7;
    const int lane2 = (lane & 15) + c16*16;
    #pragma unroll
    for (int ct = 0; ct < 4; ++ct){
      PK2 v;
      v.h[0] = __builtin_amdgcn_cvt_pkrtz(fmaxf(acc[rt][ct][0] + bq.x, 0.f),
                                          fmaxf(acc[rt][ct][1] + bq.y, 0.f));
      v.h[1] = __builtin_amdgcn_cvt_pkrtz(fmaxf(acc[rt][ct][2] + bq.z, 0.f),
                                          fmaxf(acc[rt][ct][3] + bq.w, 0.f));
      *(uint2*)&Hb[((kt2*4 + ct)*64 + lane2)*8 + j0] = v.u;
      acc[rt][ct] = zz;
    }
  }
  __syncthreads();

  // -------- layer 2: K=256, fully unrolled, 2-deep A-frag pipeline --------
  __builtin_amdgcn_s_setprio(1);
#define MFMA4(AR, RT) \
    acc[RT][0] = MFMA_(AR, Bv0, acc[RT][0]); \
    acc[RT][1] = MFMA_(AR, Bv1, acc[RT][1]); \
    acc[RT][2] = MFMA_(AR, Bv2, acc[RT][2]); \
    acc[RT][3] = MFMA_(AR, Bv3, acc[RT][3]);
#define L2STEP(KT, ACUR) { \
    f16x8 Bv0 = *(f16x8*)&Hb[(((KT)*4 + 0)*64 + lane)*8]; \
    f16x8 Bv1 = *(f16x8*)&Hb[(((KT)*4 + 1)*64 + lane)*8]; \
    f16x8 Bv2 = *(f16x8*)&Hb[(((KT)*4 + 2)*64 + lane)*8]; \
    f16x8 Bv3 = *(f16x8*)&Hb[(((KT)*4 + 3)*64 + lane)*8]; \
    MFMA4(ACUR[0], 0); \
    if ((KT) + 2 < 8) ACUR[0] = *(const f16x8*)&w2f[(((wr + 0)*8 + (KT) + 2)*64 + lane)*8]; \
    MFMA4(ACUR[1], 1); \
    if ((KT) + 2 < 8) ACUR[1] = *(const f16x8*)&w2f[(((wr + 1)*8 + (KT) + 2)*64 + lane)*8]; \
    MFMA4(ACUR[2], 2); \
    if ((KT) + 2 < 8) ACUR[2] = *(const f16x8*)&w2f[(((wr + 2)*8 + (KT) + 2)*64 + lane)*8]; \
    MFMA4(ACUR[3], 3); \
    if ((KT) + 2 < 8) ACUR[3] = *(const f16x8*)&w2f[(((wr + 3)*8 + (KT) + 2)*64 + lane)*8]; \
  }
  L2STEP(0, A0)
  L2STEP(1, A1)
  L2STEP(2, A0)
  L2STEP(3, A1)
  L2STEP(4, A0)
  L2STEP(5, A1)
  L2STEP(6, A0)
  L2STEP(7, A1)
#undef L2STEP
#undef MFMA4
  __builtin_amdgcn_s_setprio(0);

  // ---- preload layer-3 A-frags (hide under epilogue L2) ----
  f16x8 W3v[8];
  #pragma unroll
  for (int kt = 0; kt < 8; ++kt) W3v[kt] = *(const f16x8*)&w3f[(kt*64 + lane)*8];
  __syncthreads();

  // -------- epilogue L2: bias+relu -> f16 fragment order (Bh2), pkrtz --------
  #pragma unroll
  for (int rt = 0; rt < 4; ++rt){
    const int row0 = w*64 + rt*16 + ((lane >> 4) << 2);
    const float4 bq = *(const float4*)&b2[row0];
    const int kt2 = row0 >> 5, c16 = (row0 >> 3) & 3, j0 = row0 & 7;
    const int lane2 = (lane & 15) + c16*16;
    #pragma unroll
    for (int ct = 0; ct < 4; ++ct){
      PK2 v;
      v.h[0] = __builtin_amdgcn_cvt_pkrtz(fmaxf(acc[rt][ct][0] + bq.x, 0.f),
                                          fmaxf(acc[rt][ct][1] + bq.y, 0.f));
      v.h[1] = __builtin_amdgcn_cvt_pkrtz(fmaxf(acc[rt][ct][2] + bq.z, 0.f),
                                          fmaxf(acc[rt][ct][3] + bq.w, 0.f));
      *(uint2*)&Hb[((kt2*4 + ct)*64 + lane2)*8 + j0] = v.u;
    }
  }
  __syncthreads();

  // -------- layer 3: rows 0..2, wave w handles col-tile w --------
  f32x4 a3 = zz;
  __builtin_amdgcn_s_setprio(1);
  #pragma unroll
  for (int kt = 0; kt < 8; ++kt){
    f16x8 B = *(f16x8*)&Hb[((kt*4 + w)*64 + lane)*8];
    a3 = MFMA_(W3v[kt], B, a3);
  }
  __builtin_amdgcn_s_setprio(0);
  if (lane < 16){
    const float ox = a3[0] + b3[0];
    const float oy = a3[1] + b3[1];
    const float oz = a3[2] + b3[2];
    const float nrm = sqrtf(ox*ox + oy*oy + oz*oz);
    const float rg_ = fmaxf(nrm - (float)0.10825317547305482, 0.f);
    const int pt = w*16 + lane;
    const int cell = cells[pt];
    const float fx = ((float)(cell >> 8)        + 0.5f) * 0.0625f - 0.5f;
    const float fy = ((float)((cell >> 4) & 15) + 0.5f) * 0.0625f - 0.5f;
    const float fz = ((float)(cell & 15)        + 0.5f) * 0.0625f - 0.5f;
    const int pidx = p0 + pt;
    out[b*49152 +          pidx] = ox + fx;
    out[b*49152 + 16384 +  pidx] = oy + fy;
    out[b*49152 + 32768 +  pidx] = oz + fz;
    out[786432  + b*16384 + pidx] = rg_;
  }
}

extern "C" void kernel_launch(void* const* d_in, const int* in_sizes, int n_in,
                              void* d_out, int out_size, void* d_ws, size_t ws_size,
                              hipStream_t stream){
  const float* x     = (const float*)d_in[0];
  const float* dens  = (const float*)d_in[1];
  const float* noise = (const float*)d_in[2];
  const float* W1    = (const float*)d_in[3];
  const float* b1    = (const float*)d_in[4];
  const float* W2    = (const float*)d_in[5];
  const float* b2    = (const float*)d_in[6];
  const float* W3    = (const float*)d_in[7];
  const float* b3    = (const float*)d_in[8];

  char* ws = (char*)d_ws;
  int*      pc   = (int*)(ws + 0);
  _Float16* w1f  = (_Float16*)(ws + 1048576);
  _Float16* w2f  = (_Float16*)(ws + 1081344);
  _Float16* w3f  = (_Float16*)(ws + 1212416);
  float*    w1n  = (float*)(ws + 1220608);
  float*    out  = (float*)d_out;

  kP<<<dim3(59),      dim3(256), 0, stream>>>(dens, pc, W1, W2, W3, w1f, w2f, w3f, w1n);
  kE<<<dim3(256, 16), dim3(256), 0, stream>>>(x, noise, w1f, w2f, w3f, w1n,
                                              b1, b2, b3, pc, out);
}

// Round 6
// 89.594 us; speedup vs baseline: 1.0097x; 1.0097x over previous
//
#include <hip/hip_runtime.h>

typedef unsigned long long u64;
typedef _Float16 f16x8 __attribute__((ext_vector_type(8)));
typedef float    f32x4 __attribute__((ext_vector_type(4)));
typedef __fp16   fp16x2 __attribute__((ext_vector_type(2)));

#define G_    4096
#define NPTS  16384

union H8 { _Float16 h[8]; uint4 u; };
union PK2 { fp16x2 h[2]; uint2 u; };
union PK4 { fp16x2 h[4]; uint4 u; };

#define MFMA_(A_,B_,C_) __builtin_amdgcn_mfma_f32_16x16x32_f16((A_),(B_),(C_),0,0,0)

// ---------------- ws layout (bytes) ----------------
// pc   i32 [16][16384]    @ 0        (1048576)
// w1f  f16 [16][2][64][8] @ 1048576  (32768)   A-frag order, K=64 (x channels only)
// w2f  f16 [16][8][64][8] @ 1081344  (131072)
// w3f  f16 [8][64][8]     @ 1212416  (8192)    rows 3..15 zero
// w1n  f32 [256][2]       @ 1220608  (2048)    W1 cols 64,65 (noise channels)
// total 1222656

// ---- merged prep: blocks 0..15 = sampling (per batch); blocks 16..58 = weight bake ----
__global__ __launch_bounds__(256) void kP(const float* __restrict__ dens,
                                          int* __restrict__ pc,
                                          const float* __restrict__ W1,
                                          const float* __restrict__ W2,
                                          const float* __restrict__ W3,
                                          _Float16* __restrict__ w1f,
                                          _Float16* __restrict__ w2f,
                                          _Float16* __restrict__ w3f,
                                          float* __restrict__ w1n){
  __shared__ double sred[256];
  __shared__ u64  keys[4096];     // 32 KB
  __shared__ int  nvs[4096];      // 16 KB
  __shared__ int  binidx[4096];   // 16 KB
  __shared__ int  hist[1024];
  __shared__ int  cab[1024];
  __shared__ int  scan[256];
  __shared__ float Sf;
  __shared__ int  remS, BstarS, needS, cntS;
  const int t = threadIdx.x;

  if (blockIdx.x >= 16){
    // ---------------- weight bake path ----------------
    const int e = (blockIdx.x - 16)*256 + t;   // 11008 entries
    H8 v;
    if (e < 8192){                                 // w2f: [RT 16][kt 8][lane 64]
      const int RT = e >> 9, kt = (e >> 6) & 7, l = e & 63;
      const int m = RT*16 + (l & 15), k = kt*32 + ((l >> 4) << 3);
      #pragma unroll
      for (int j = 0; j < 8; ++j) v.h[j] = (_Float16)W2[m*256 + k + j];
      *(uint4*)&w2f[e*8] = v.u;
    } else if (e < 10240){                         // w1f: [RT 16][kt 2][lane 64]
      const int e2 = e - 8192;
      const int RT = e2 >> 7, r2 = e2 & 127, kt = r2 >> 6, l = r2 & 63;
      const int m = RT*16 + (l & 15), k = kt*32 + ((l >> 4) << 3);   // k < 64
      #pragma unroll
      for (int j = 0; j < 8; ++j) v.h[j] = (_Float16)W1[m*66 + k + j];
      *(uint4*)&w1f[e2*8] = v.u;
    } else if (e < 10752){                         // w3f: [kt 8][lane 64]
      const int e3 = e - 10240;
      const int kt = e3 >> 6, l = e3 & 63;
      const int m = l & 15, k = kt*32 + ((l >> 4) << 3);
      #pragma unroll
      for (int j = 0; j < 8; ++j) v.h[j] = (m < 3) ? (_Float16)W3[m*256 + k + j] : (_Float16)0.f;
      *(uint4*)&w3f[e3*8] = v.u;
    } else if (e < 11008){                         // w1n: noise-channel cols
      const int r = e - 10752;
      w1n[r*2 + 0] = W1[r*66 + 64];
      w1n[r*2 + 1] = W1[r*66 + 65];
    }
    return;
  }

  // ---------------- sampling path (one block per batch) ----------------
  const int b = blockIdx.x;
  const float* d = dens + b*G_;

  for (int j = t; j < 1024; j += 256) hist[j] = 0;
  if (t == 0) cntS = 0;

  // exact same summation pattern as passing rounds: per-thread d[t+256j], tree over 256
  double s = 0.0;
  for (int j = 0; j < 16; ++j) s += (double)d[t + 256*j];
  sred[t] = s; __syncthreads();
  for (int off = 128; off > 0; off >>= 1){
    if (t < off) sred[t] += sred[t + off];
    __syncthreads();
  }
  if (t == 0) Sf = (float)sred[0];
  __syncthreads();
  const float S = Sf;

  int bi[16]; int bs = 0;
  #pragma unroll
  for (int j = 0; j < 16; ++j){
    const int i = t + 256*j;
    const float p  = d[i] / S;
    const float sc = p * 16384.0f;     // exact (x2^14)
    const float fl = floorf(sc);
    const float fr = sc - fl;          // exact
    bi[j] = (int)fl; bs += bi[j];
    const unsigned fb = __float_as_uint(fr);
    keys[i] = ((u64)fb << 12) | (u64)(4095 - i);
    atomicAdd(&hist[fb >> 20], 1);
  }
  scan[t] = bs; __syncthreads();
  for (int off = 128; off > 0; off >>= 1){
    if (t < off) scan[t] += scan[t + off];
    __syncthreads();
  }
  if (t == 0) remS = 16384 - scan[0];
  __syncthreads();
  const int rem = remS;

  // suffix-scan histogram (1024 bins, 4/thread) -> cab[q] = #keys in bins > q
  const int h0 = hist[4*t], h1 = hist[4*t+1], h2 = hist[4*t+2], h3 = hist[4*t+3];
  const int gs = h0 + h1 + h2 + h3;
  __syncthreads();
  scan[t] = gs; __syncthreads();
  for (int off = 1; off < 256; off <<= 1){
    const int v2 = (t + off < 256) ? scan[t + off] : 0;
    __syncthreads();
    scan[t] += v2;
    __syncthreads();
  }
  const int sAfter = scan[t] - gs;
  cab[4*t+3] = sAfter;
  cab[4*t+2] = sAfter + h3;
  cab[4*t+1] = sAfter + h3 + h2;
  cab[4*t+0] = sAfter + h3 + h2 + h1;
  if (t == 0){ BstarS = 0x7fffffff; needS = 0; }
  __syncthreads();
  if (rem > 0){
    const int ca[4] = {cab[4*t], cab[4*t+1], cab[4*t+2], cab[4*t+3]};
    const int hh[4] = {h0, h1, h2, h3};
    #pragma unroll
    for (int q = 0; q < 4; ++q)
      if (ca[q] < rem && rem <= ca[q] + hh[q]){ BstarS = 4*t + q; needS = rem - ca[q]; }
  }
  __syncthreads();
  const int Bstar = BstarS, need = needS;

  #pragma unroll
  for (int j = 0; j < 16; ++j){
    const int i = t + 256*j;
    const int bin = (int)(keys[i] >> 32);
    nvs[i] = bi[j] + ((bin > Bstar) ? 1 : 0);
    if (bin == Bstar){ const int pos = atomicAdd(&cntS, 1); binidx[pos] = i; }
  }
  __syncthreads();
  const int cnt = cntS;
  for (int p = t; p < cnt; p += 256){
    const u64 K = keys[binidx[p]];
    int r = 0;
    for (int q = 0; q < cnt; ++q) r += (keys[binidx[q]] > K) ? 1 : 0;
    if (r < need) nvs[binidx[p]] += 1;
  }
  __syncthreads();

  // prefix + expand (thread t owns cells t*16..t*16+15)
  int loc[16]; int ls = 0;
  #pragma unroll
  for (int j = 0; j < 16; ++j){ loc[j] = nvs[t*16 + j]; ls += loc[j]; }
  __syncthreads();
  scan[t] = ls; __syncthreads();
  for (int off = 1; off < 256; off <<= 1){
    const int v2 = (t >= off) ? scan[t - off] : 0;
    __syncthreads();
    scan[t] += v2;
    __syncthreads();
  }
  int off0 = scan[t] - ls;
  int* o = pc + b*NPTS;
  #pragma unroll
  for (int j = 0; j < 16; ++j){
    const int c = t*16 + j;
    for (int r = 0; r < loc[j]; ++r) o[off0++] = c;
  }
}

// ---- fused MLP via f16 MFMA: 128 points/block, 4 waves, wave = 64 rows x 128 pts ----
// acc = 4rt x 8ct x f32x4 = 128 regs; cap 256 @ 2 waves/SIMD -> no spill, 2 blocks/CU.
__global__ __launch_bounds__(256, 2) void kE(
    const float* __restrict__ x, const float* __restrict__ noise,
    const _Float16* __restrict__ w1f, const _Float16* __restrict__ w2f,
    const _Float16* __restrict__ w3f, const float* __restrict__ w1n,
    const float* __restrict__ b1, const float* __restrict__ b2, const float* __restrict__ b3,
    const int* __restrict__ pc, float* __restrict__ out)
{
  __shared__ _Float16 Hb[32768];   // 64KB; reused: Bin(16KB) -> Bh1(64KB) -> Bh2(64KB)
  __shared__ float rndS[2][128];
  const int b = blockIdx.y, p0 = blockIdx.x*128, tid = threadIdx.x;
  const int w = tid >> 6, lane = tid & 63;

  // ---- stage noise ----
  {
    const int rr = tid >> 7, p = tid & 127;
    rndS[rr][p] = noise[(b*2 + rr)*NPTS + p0 + p]*2.f - 1.f;
  }
  // ---- stage layer-1 input (fragment order); task e = (pt, koct) ----
  #pragma unroll
  for (int i = 0; i < 4; ++i){
    const int e = tid + 256*i;                 // 0..1023
    const int pt = e >> 3, koct = e & 7;       // koct*8 = kbase in 0..56
    const int cell = pc[b*NPTS + p0 + pt];
    const int kt = koct >> 2, k2 = koct & 3;
    const int lane2 = (pt & 15) + k2*16, ct = pt >> 4;
    const float* xb = x + ((size_t)(b*64 + koct*8))*G_ + cell;
    float xv[8];
    #pragma unroll
    for (int j = 0; j < 8; ++j) xv[j] = xb[(size_t)j*G_];
    PK4 v;
    v.h[0] = __builtin_amdgcn_cvt_pkrtz(xv[0], xv[1]);
    v.h[1] = __builtin_amdgcn_cvt_pkrtz(xv[2], xv[3]);
    v.h[2] = __builtin_amdgcn_cvt_pkrtz(xv[4], xv[5]);
    v.h[3] = __builtin_amdgcn_cvt_pkrtz(xv[6], xv[7]);
    *(uint4*)&Hb[((kt*8 + ct)*64 + lane2)*8] = v.u;
  }
  __syncthreads();

  f32x4 acc[4][8];
  const f32x4 zz = {0.f, 0.f, 0.f, 0.f};
  #pragma unroll
  for (int rt = 0; rt < 4; ++rt)
    #pragma unroll
    for (int ct = 0; ct < 8; ++ct) acc[rt][ct] = zz;

  const int wr = w*4;

  // -------- layer 1: K=64 (2 k-tiles, x channels only) --------
  __builtin_amdgcn_s_setprio(1);
  #pragma unroll
  for (int kt = 0; kt < 2; ++kt){
    f16x8 B[8];
    #pragma unroll
    for (int ct = 0; ct < 8; ++ct) B[ct] = *(f16x8*)&Hb[((kt*8 + ct)*64 + lane)*8];
    #pragma unroll
    for (int rt = 0; rt < 4; ++rt){
      f16x8 A = *(const f16x8*)&w1f[(((wr + rt)*2 + kt)*64 + lane)*8];
      #pragma unroll
      for (int ct = 0; ct < 8; ++ct)
        acc[rt][ct] = MFMA_(A, B[ct], acc[rt][ct]);
    }
  }
  __builtin_amdgcn_s_setprio(0);

  // ---- rank-2 noise update (f32): acc += w1[:,64] x rnd0 + w1[:,65] x rnd1 ----
  {
    const int m16 = lane & 15, khi = lane >> 4;
    float rn0[8], rn1[8];
    #pragma unroll
    for (int ct = 0; ct < 8; ++ct){
      rn0[ct] = rndS[0][ct*16 + m16];
      rn1[ct] = rndS[1][ct*16 + m16];
    }
    #pragma unroll
    for (int rt = 0; rt < 4; ++rt){
      const int row0 = w*64 + rt*16 + khi*4;
      const float4 wa = *(const float4*)&w1n[row0*2];       // rows row0,row0+1
      const float4 wb = *(const float4*)&w1n[row0*2 + 4];   // rows row0+2,row0+3
      #pragma unroll
      for (int ct = 0; ct < 8; ++ct){
        acc[rt][ct][0] += wa.x*rn0[ct] + wa.y*rn1[ct];
        acc[rt][ct][1] += wa.z*rn0[ct] + wa.w*rn1[ct];
        acc[rt][ct][2] += wb.x*rn0[ct] + wb.y*rn1[ct];
        acc[rt][ct][3] += wb.z*rn0[ct] + wb.w*rn1[ct];
      }
    }
  }
  __syncthreads();

  // -------- epilogue L1: bias+relu -> f16 fragment order (Bh1), pkrtz --------
  #pragma unroll
  for (int rt = 0; rt < 4; ++rt){
    const int row0 = w*64 + rt*16 + ((lane >> 4) << 2);
    const float4 bq = *(const float4*)&b1[row0];
    const int kt2 = row0 >> 5, c16 = (row0 >> 3) & 3, j0 = row0 & 7;
    const int lane2 = (lane & 15) + c16*16;
    #pragma unroll
    for (int ct = 0; ct < 8; ++ct){
      PK2 v;
      v.h[0] = __builtin_amdgcn_cvt_pkrtz(fmaxf(acc[rt][ct][0] + bq.x, 0.f),
                                          fmaxf(acc[rt][ct][1] + bq.y, 0.f));
      v.h[1] = __builtin_amdgcn_cvt_pkrtz(fmaxf(acc[rt][ct][2] + bq.z, 0.f),
                                          fmaxf(acc[rt][ct][3] + bq.w, 0.f));
      *(uint2*)&Hb[((kt2*8 + ct)*64 + lane2)*8 + j0] = v.u;
      acc[rt][ct] = zz;
    }
  }
  __syncthreads();

  // -------- layer 2: K=256 (8 k-tiles), simple loop (compiler schedules) --------
  __builtin_amdgcn_s_setprio(1);
  #pragma unroll 2
  for (int kt = 0; kt < 8; ++kt){
    f16x8 B[8];
    #pragma unroll
    for (int ct = 0; ct < 8; ++ct) B[ct] = *(f16x8*)&Hb[((kt*8 + ct)*64 + lane)*8];
    #pragma unroll
    for (int rt = 0; rt < 4; ++rt){
      f16x8 A = *(const f16x8*)&w2f[(((wr + rt)*8 + kt)*64 + lane)*8];
      #pragma unroll
      for (int ct = 0; ct < 8; ++ct)
        acc[rt][ct] = MFMA_(A, B[ct], acc[rt][ct]);
    }
  }
  __builtin_amdgcn_s_setprio(0);

  // ---- preload layer-3 A-frags (hide under epilogue L2) ----
  f16x8 W3v[8];
  #pragma unroll
  for (int kt = 0; kt < 8; ++kt) W3v[kt] = *(const f16x8*)&w3f[(kt*64 + lane)*8];
  __syncthreads();

  // -------- epilogue L2: bias+relu -> f16 fragment order (Bh2), pkrtz --------
  #pragma unroll
  for (int rt = 0; rt < 4; ++rt){
    const int row0 = w*64 + rt*16 + ((lane >> 4) << 2);
    const float4 bq = *(const float4*)&b2[row0];
    const int kt2 = row0 >> 5, c16 = (row0 >> 3) & 3, j0 = row0 & 7;
    const int lane2 = (lane & 15) + c16*16;
    #pragma unroll
    for (int ct = 0; ct < 8; ++ct){
      PK2 v;
      v.h[0] = __builtin_amdgcn_cvt_pkrtz(fmaxf(acc[rt][ct][0] + bq.x, 0.f),
                                          fmaxf(acc[rt][ct][1] + bq.y, 0.f));
      v.h[1] = __builtin_amdgcn_cvt_pkrtz(fmaxf(acc[rt][ct][2] + bq.z, 0.f),
                                          fmaxf(acc[rt][ct][3] + bq.w, 0.f));
      *(uint2*)&Hb[((kt2*8 + ct)*64 + lane2)*8 + j0] = v.u;
    }
  }
  __syncthreads();

  // -------- layer 3: rows 0..2; wave w handles col-tiles {2w, 2w+1} --------
  f32x4 a3[2] = {zz, zz};
  __builtin_amdgcn_s_setprio(1);
  #pragma unroll
  for (int kt = 0; kt < 8; ++kt){
    f16x8 B0 = *(f16x8*)&Hb[((kt*8 + w*2 + 0)*64 + lane)*8];
    f16x8 B1 = *(f16x8*)&Hb[((kt*8 + w*2 + 1)*64 + lane)*8];
    a3[0] = MFMA_(W3v[kt], B0, a3[0]);
    a3[1] = MFMA_(W3v[kt], B1, a3[1]);
  }
  __builtin_amdgcn_s_setprio(0);
  if (lane < 16){
    #pragma unroll
    for (int q = 0; q < 2; ++q){
      const float ox = a3[q][0] + b3[0];
      const float oy = a3[q][1] + b3[1];
      const float oz = a3[q][2] + b3[2];
      const float nrm = sqrtf(ox*ox + oy*oy + oz*oz);
      const float rg_ = fmaxf(nrm - (float)0.10825317547305482, 0.f);
      const int pt = (w*2 + q)*16 + lane;
      const int pidx = p0 + pt;
      const int cell = pc[b*NPTS + pidx];
      const float fx = ((float)(cell >> 8)        + 0.5f) * 0.0625f - 0.5f;
      const float fy = ((float)((cell >> 4) & 15) + 0.5f) * 0.0625f - 0.5f;
      const float fz = ((float)(cell & 15)        + 0.5f) * 0.0625f - 0.5f;
      out[b*49152 +          pidx] = ox + fx;
      out[b*49152 + 16384 +  pidx] = oy + fy;
      out[b*49152 + 32768 +  pidx] = oz + fz;
      out[786432  + b*16384 + pidx] = rg_;
    }
  }
}

extern "C" void kernel_launch(void* const* d_in, const int* in_sizes, int n_in,
                              void* d_out, int out_size, void* d_ws, size_t ws_size,
                              hipStream_t stream){
  const float* x     = (const float*)d_in[0];
  const float* dens  = (const float*)d_in[1];
  const float* noise = (const float*)d_in[2];
  const float* W1    = (const float*)d_in[3];
  const float* b1    = (const float*)d_in[4];
  const float* W2    = (const float*)d_in[5];
  const float* b2    = (const float*)d_in[6];
  const float* W3    = (const float*)d_in[7];
  const float* b3    = (const float*)d_in[8];

  char* ws = (char*)d_ws;
  int*      pc   = (int*)(ws + 0);
  _Float16* w1f  = (_Float16*)(ws + 1048576);
  _Float16* w2f  = (_Float16*)(ws + 1081344);
  _Float16* w3f  = (_Float16*)(ws + 1212416);
  float*    w1n  = (float*)(ws + 1220608);
  float*    out  = (float*)d_out;

  kP<<<dim3(59),      dim3(256), 0, stream>>>(dens, pc, W1, W2, W3, w1f, w2f, w3f, w1n);
  kE<<<dim3(128, 16), dim3(256), 0, stream>>>(x, noise, w1f, w2f, w3f, w1n,
                                              b1, b2, b3, pc, out);
}

// Round 7
// 84.170 us; speedup vs baseline: 1.0748x; 1.0644x over previous
//
#include <hip/hip_runtime.h>

typedef unsigned long long u64;
typedef _Float16 f16x8 __attribute__((ext_vector_type(8)));
typedef float    f32x4 __attribute__((ext_vector_type(4)));
typedef __fp16   fp16x2 __attribute__((ext_vector_type(2)));

#define G_    4096
#define NPTS  16384

union H8 { _Float16 h[8]; uint4 u; };
union PK2 { fp16x2 h[2]; uint2 u; };
union PK4 { fp16x2 h[4]; uint4 u; };

#define MFMA_(A_,B_,C_) __builtin_amdgcn_mfma_f32_16x16x32_f16((A_),(B_),(C_),0,0,0)

// ---------------- ws layout (bytes) ----------------
// pc   i32 [16][16384]    @ 0        (1048576)
// w1f  f16 [16][3][64][8] @ 1048576  (49152)   A-frag order, 3 k-tiles (k=64..95 pad/noise)
// w2f  f16 [16][8][64][8] @ 1097728  (131072)
// w3f  f16 [8][64][8]     @ 1228800  (8192)    rows 3..15 zero
// xT   f16 [16][4096][64] @ 1236992  (8388608) transposed+f16 x (only if ws fits)
// total 9625600

#define OFF_W1F 1048576
#define OFF_W2F 1097728
#define OFF_W3F 1228800
#define OFF_XT  1236992
#define WS_NEED (OFF_XT + 8388608)

// ---- merged prep ----
// blocks 0..15   : sampling (one per batch)
// blocks 16..61  : weight bake (11776 H8 entries)
// blocks 62..317 : x transpose -> f16 (only launched when use_xt)
__global__ __launch_bounds__(256) void kP(const float* __restrict__ dens,
                                          int* __restrict__ pc,
                                          const float* __restrict__ W1,
                                          const float* __restrict__ W2,
                                          const float* __restrict__ W3,
                                          const float* __restrict__ x,
                                          _Float16* __restrict__ w1f,
                                          _Float16* __restrict__ w2f,
                                          _Float16* __restrict__ w3f,
                                          _Float16* __restrict__ xT){
  __shared__ double sred[256];
  __shared__ u64  keys[4096];     // 32 KB
  __shared__ int  nvs[4096];      // 16 KB
  __shared__ int  binidx[4096];   // 16 KB
  __shared__ int  hist[1024];
  __shared__ int  cab[1024];
  __shared__ int  scan[256];
  __shared__ float Sf;
  __shared__ int  remS, BstarS, needS, cntS;
  const int t = threadIdx.x;

  if (blockIdx.x >= 62){
    // ---------------- x transpose path: [64][4096] f32 -> [4096][64] f16 ----------------
    const int idx = blockIdx.x - 62;          // 0..255
    const int b = idx >> 4, blk = idx & 15;
    const int cell = blk*256 + t;
    const float* xb = x + ((size_t)b*64)*G_ + cell;
    _Float16* xo = xT + ((size_t)(b*G_ + cell))*64;
    #pragma unroll
    for (int c8 = 0; c8 < 8; ++c8){
      float a[8];
      #pragma unroll
      for (int j = 0; j < 8; ++j) a[j] = xb[(size_t)(c8*8 + j)*G_];
      PK4 v;
      v.h[0] = __builtin_amdgcn_cvt_pkrtz(a[0], a[1]);
      v.h[1] = __builtin_amdgcn_cvt_pkrtz(a[2], a[3]);
      v.h[2] = __builtin_amdgcn_cvt_pkrtz(a[4], a[5]);
      v.h[3] = __builtin_amdgcn_cvt_pkrtz(a[6], a[7]);
      *(uint4*)&xo[c8*8] = v.u;
    }
    return;
  }

  if (blockIdx.x >= 16){
    // ---------------- weight bake path ----------------
    const int e = (blockIdx.x - 16)*256 + t;   // 11776 entries
    H8 v;
    if (e < 8192){                                 // w2f: [RT 16][kt 8][lane 64]
      const int RT = e >> 9, kt = (e >> 6) & 7, l = e & 63;
      const int m = RT*16 + (l & 15), k = kt*32 + ((l >> 4) << 3);
      #pragma unroll
      for (int j = 0; j < 8; ++j) v.h[j] = (_Float16)W2[m*256 + k + j];
      *(uint4*)&w2f[e*8] = v.u;
    } else if (e < 11264){                         // w1f: [RT 16][kt 3][lane 64]
      const int e2 = e - 8192;
      const int RT = e2 / 192, r2 = e2 % 192, kt = r2 >> 6, l = r2 & 63;
      const int m = RT*16 + (l & 15), k = kt*32 + ((l >> 4) << 3);
      #pragma unroll
      for (int j = 0; j < 8; ++j) v.h[j] = (k + j < 66) ? (_Float16)W1[m*66 + k + j] : (_Float16)0.f;
      *(uint4*)&w1f[e2*8] = v.u;
    } else if (e < 11776){                         // w3f: [kt 8][lane 64]
      const int e3 = e - 11264;
      const int kt = e3 >> 6, l = e3 & 63;
      const int m = l & 15, k = kt*32 + ((l >> 4) << 3);
      #pragma unroll
      for (int j = 0; j < 8; ++j) v.h[j] = (m < 3) ? (_Float16)W3[m*256 + k + j] : (_Float16)0.f;
      *(uint4*)&w3f[e3*8] = v.u;
    }
    return;
  }

  // ---------------- sampling path (one block per batch) ----------------
  const int b = blockIdx.x;
  const float* d = dens + b*G_;

  for (int j = t; j < 1024; j += 256) hist[j] = 0;
  if (t == 0) cntS = 0;

  // exact same summation pattern as passing rounds: per-thread d[t+256j], tree over 256
  double s = 0.0;
  for (int j = 0; j < 16; ++j) s += (double)d[t + 256*j];
  sred[t] = s; __syncthreads();
  for (int off = 128; off > 0; off >>= 1){
    if (t < off) sred[t] += sred[t + off];
    __syncthreads();
  }
  if (t == 0) Sf = (float)sred[0];
  __syncthreads();
  const float S = Sf;

  int bi[16]; int bs = 0;
  #pragma unroll
  for (int j = 0; j < 16; ++j){
    const int i = t + 256*j;
    const float p  = d[i] / S;
    const float sc = p * 16384.0f;     // exact (x2^14)
    const float fl = floorf(sc);
    const float fr = sc - fl;          // exact
    bi[j] = (int)fl; bs += bi[j];
    const unsigned fb = __float_as_uint(fr);
    keys[i] = ((u64)fb << 12) | (u64)(4095 - i);
    atomicAdd(&hist[fb >> 20], 1);
  }
  scan[t] = bs; __syncthreads();
  for (int off = 128; off > 0; off >>= 1){
    if (t < off) scan[t] += scan[t + off];
    __syncthreads();
  }
  if (t == 0) remS = 16384 - scan[0];
  __syncthreads();
  const int rem = remS;

  // suffix-scan histogram (1024 bins, 4/thread) -> cab[q] = #keys in bins > q
  const int h0 = hist[4*t], h1 = hist[4*t+1], h2 = hist[4*t+2], h3 = hist[4*t+3];
  const int gs = h0 + h1 + h2 + h3;
  __syncthreads();
  scan[t] = gs; __syncthreads();
  for (int off = 1; off < 256; off <<= 1){
    const int v2 = (t + off < 256) ? scan[t + off] : 0;
    __syncthreads();
    scan[t] += v2;
    __syncthreads();
  }
  const int sAfter = scan[t] - gs;
  cab[4*t+3] = sAfter;
  cab[4*t+2] = sAfter + h3;
  cab[4*t+1] = sAfter + h3 + h2;
  cab[4*t+0] = sAfter + h3 + h2 + h1;
  if (t == 0){ BstarS = 0x7fffffff; needS = 0; }
  __syncthreads();
  if (rem > 0){
    const int ca[4] = {cab[4*t], cab[4*t+1], cab[4*t+2], cab[4*t+3]};
    const int hh[4] = {h0, h1, h2, h3};
    #pragma unroll
    for (int q = 0; q < 4; ++q)
      if (ca[q] < rem && rem <= ca[q] + hh[q]){ BstarS = 4*t + q; needS = rem - ca[q]; }
  }
  __syncthreads();
  const int Bstar = BstarS, need = needS;

  #pragma unroll
  for (int j = 0; j < 16; ++j){
    const int i = t + 256*j;
    const int bin = (int)(keys[i] >> 32);
    nvs[i] = bi[j] + ((bin > Bstar) ? 1 : 0);
    if (bin == Bstar){ const int pos = atomicAdd(&cntS, 1); binidx[pos] = i; }
  }
  __syncthreads();
  const int cnt = cntS;
  for (int p = t; p < cnt; p += 256){
    const u64 K = keys[binidx[p]];
    int r = 0;
    for (int q = 0; q < cnt; ++q) r += (keys[binidx[q]] > K) ? 1 : 0;
    if (r < need) nvs[binidx[p]] += 1;
  }
  __syncthreads();

  // prefix + expand (thread t owns cells t*16..t*16+15)
  int loc[16]; int ls = 0;
  #pragma unroll
  for (int j = 0; j < 16; ++j){ loc[j] = nvs[t*16 + j]; ls += loc[j]; }
  __syncthreads();
  scan[t] = ls; __syncthreads();
  for (int off = 1; off < 256; off <<= 1){
    const int v2 = (t >= off) ? scan[t - off] : 0;
    __syncthreads();
    scan[t] += v2;
    __syncthreads();
  }
  int off0 = scan[t] - ls;
  int* o = pc + b*NPTS;
  #pragma unroll
  for (int j = 0; j < 16; ++j){
    const int c = t*16 + j;
    for (int r = 0; r < loc[j]; ++r) o[off0++] = c;
  }
}

// ---- fused MLP via f16 MFMA: 64 points/block, 4 waves, wave = 64 rows x 64 pts ----
template<bool USE_XT>
__global__ __launch_bounds__(256, 3) void kE(
    const float* __restrict__ x, const _Float16* __restrict__ xT,
    const float* __restrict__ noise,
    const _Float16* __restrict__ w1f, const _Float16* __restrict__ w2f,
    const _Float16* __restrict__ w3f,
    const float* __restrict__ b1, const float* __restrict__ b2, const float* __restrict__ b3,
    const int* __restrict__ pc, float* __restrict__ out)
{
  __shared__ _Float16 Hb[16384];   // 32KB; reused: Bin(12KB) -> Bh1(32KB) -> Bh2(32KB)
  __shared__ int cells[64];
  const int b = blockIdx.y, p0 = blockIdx.x*64, tid = threadIdx.x;
  const int w = tid >> 6, lane = tid & 63;

  if (tid < 64) cells[tid] = pc[b*NPTS + p0 + tid];

  // ---- stage noise k-tile (kt=2): rows k=64,65 = noise, rest zero ----
  {
    const int ct = tid >> 6, l2 = tid & 63;
    const int k2 = l2 >> 4, pt = ct*16 + (l2 & 15);
    PK4 v; v.u = make_uint4(0u, 0u, 0u, 0u);
    if (k2 == 0){
      const float n0 = noise[(b*2 + 0)*NPTS + p0 + pt]*2.f - 1.f;
      const float n1 = noise[(b*2 + 1)*NPTS + p0 + pt]*2.f - 1.f;
      v.h[0] = __builtin_amdgcn_cvt_pkrtz(n0, n1);
    }
    *(uint4*)&Hb[((2*4 + ct)*64 + l2)*8] = v.u;
  }

  // ---- stage layer-1 x k-tiles (kt=0,1); task e = (pt 64, koct 8) ----
  #pragma unroll
  for (int i = 0; i < 2; ++i){
    const int e = tid + 256*i;                 // 0..511
    const int pt = e >> 3, koct = e & 7;
    const int cell = pc[b*NPTS + p0 + pt];
    const int kt = koct >> 2, k2 = koct & 3;
    const int lane2 = (pt & 15) + k2*16, ct = pt >> 4;
    if (USE_XT){
      const uint4 v = *(const uint4*)&xT[((size_t)(b*G_ + cell))*64 + koct*8];
      *(uint4*)&Hb[((kt*4 + ct)*64 + lane2)*8] = v;
    } else {
      const float* xb = x + ((size_t)(b*64 + koct*8))*G_ + cell;
      float a[8];
      #pragma unroll
      for (int j = 0; j < 8; ++j) a[j] = xb[(size_t)j*G_];
      PK4 v;
      v.h[0] = __builtin_amdgcn_cvt_pkrtz(a[0], a[1]);
      v.h[1] = __builtin_amdgcn_cvt_pkrtz(a[2], a[3]);
      v.h[2] = __builtin_amdgcn_cvt_pkrtz(a[4], a[5]);
      v.h[3] = __builtin_amdgcn_cvt_pkrtz(a[6], a[7]);
      *(uint4*)&Hb[((kt*4 + ct)*64 + lane2)*8] = v.u;
    }
  }
  __syncthreads();

  f32x4 acc[4][4];
  const f32x4 zz = {0.f, 0.f, 0.f, 0.f};
  #pragma unroll
  for (int rt = 0; rt < 4; ++rt)
    #pragma unroll
    for (int ct = 0; ct < 4; ++ct) acc[rt][ct] = zz;

  const int wr = w*4;

  // -------- layer 1: K=96 (3 k-tiles; tile 2 = noise rows) --------
  __builtin_amdgcn_s_setprio(1);
  #pragma unroll
  for (int kt = 0; kt < 3; ++kt){
    f16x8 B[4];
    #pragma unroll
    for (int ct = 0; ct < 4; ++ct) B[ct] = *(f16x8*)&Hb[((kt*4 + ct)*64 + lane)*8];
    #pragma unroll
    for (int rt = 0; rt < 4; ++rt){
      f16x8 A = *(const f16x8*)&w1f[(((wr + rt)*3 + kt)*64 + lane)*8];
      #pragma unroll
      for (int ct = 0; ct < 4; ++ct)
        acc[rt][ct] = MFMA_(A, B[ct], acc[rt][ct]);
    }
  }
  __builtin_amdgcn_s_setprio(0);
  __syncthreads();

  // -------- epilogue L1: bias+relu -> f16 fragment order (Bh1), pkrtz --------
  #pragma unroll
  for (int rt = 0; rt < 4; ++rt){
    const int row0 = w*64 + rt*16 + ((lane >> 4) << 2);
    const float4 bq = *(const float4*)&b1[row0];
    const int kt2 = row0 >> 5, c16 = (row0 >> 3) & 3, j0 = row0 & 7;
    const int lane2 = (lane & 15) + c16*16;
    #pragma unroll
    for (int ct = 0; ct < 4; ++ct){
      PK2 v;
      v.h[0] = __builtin_amdgcn_cvt_pkrtz(fmaxf(acc[rt][ct][0] + bq.x, 0.f),
                                          fmaxf(acc[rt][ct][1] + bq.y, 0.f));
      v.h[1] = __builtin_amdgcn_cvt_pkrtz(fmaxf(acc[rt][ct][2] + bq.z, 0.f),
                                          fmaxf(acc[rt][ct][3] + bq.w, 0.f));
      *(uint2*)&Hb[((kt2*4 + ct)*64 + lane2)*8 + j0] = v.u;
      acc[rt][ct] = zz;
    }
  }
  __syncthreads();

  // -------- layer 2: K=256 (8 k-tiles), simple loop (compiler schedules) --------
  __builtin_amdgcn_s_setprio(1);
  #pragma unroll 4
  for (int kt = 0; kt < 8; ++kt){
    f16x8 B[4];
    #pragma unroll
    for (int ct = 0; ct < 4; ++ct) B[ct] = *(f16x8*)&Hb[((kt*4 + ct)*64 + lane)*8];
    #pragma unroll
    for (int rt = 0; rt < 4; ++rt){
      f16x8 A = *(const f16x8*)&w2f[(((wr + rt)*8 + kt)*64 + lane)*8];
      #pragma unroll
      for (int ct = 0; ct < 4; ++ct)
        acc[rt][ct] = MFMA_(A, B[ct], acc[rt][ct]);
    }
  }
  __builtin_amdgcn_s_setprio(0);

  // ---- preload layer-3 A-frags (hide under epilogue L2) ----
  f16x8 W3v[8];
  #pragma unroll
  for (int kt = 0; kt < 8; ++kt) W3v[kt] = *(const f16x8*)&w3f[(kt*64 + lane)*8];
  __syncthreads();

  // -------- epilogue L2: bias+relu -> f16 fragment order (Bh2), pkrtz --------
  #pragma unroll
  for (int rt = 0; rt < 4; ++rt){
    const int row0 = w*64 + rt*16 + ((lane >> 4) << 2);
    const float4 bq = *(const float4*)&b2[row0];
    const int kt2 = row0 >> 5, c16 = (row0 >> 3) & 3, j0 = row0 & 7;
    const int lane2 = (lane & 15) + c16*16;
    #pragma unroll
    for (int ct = 0; ct < 4; ++ct){
      PK2 v;
      v.h[0] = __builtin_amdgcn_cvt_pkrtz(fmaxf(acc[rt][ct][0] + bq.x, 0.f),
                                          fmaxf(acc[rt][ct][1] + bq.y, 0.f));
      v.h[1] = __builtin_amdgcn_cvt_pkrtz(fmaxf(acc[rt][ct][2] + bq.z, 0.f),
                                          fmaxf(acc[rt][ct][3] + bq.w, 0.f));
      *(uint2*)&Hb[((kt2*4 + ct)*64 + lane2)*8 + j0] = v.u;
    }
  }
  __syncthreads();

  // -------- layer 3: rows 0..2, wave w handles col-tile w --------
  f32x4 a3 = zz;
  __builtin_amdgcn_s_setprio(1);
  #pragma unroll
  for (int kt = 0; kt < 8; ++kt){
    f16x8 B = *(f16x8*)&Hb[((kt*4 + w)*64 + lane)*8];
    a3 = MFMA_(W3v[kt], B, a3);
  }
  __builtin_amdgcn_s_setprio(0);
  if (lane < 16){
    const float ox = a3[0] + b3[0];
    const float oy = a3[1] + b3[1];
    const float oz = a3[2] + b3[2];
    const float nrm = sqrtf(ox*ox + oy*oy + oz*oz);
    const float rg_ = fmaxf(nrm - (float)0.10825317547305482, 0.f);
    const int pt = w*16 + lane;
    const int cell = cells[pt];
    const float fx = ((float)(cell >> 8)        + 0.5f) * 0.0625f - 0.5f;
    const float fy = ((float)((cell >> 4) & 15) + 0.5f) * 0.0625f - 0.5f;
    const float fz = ((float)(cell & 15)        + 0.5f) * 0.0625f - 0.5f;
    const int pidx = p0 + pt;
    out[b*49152 +          pidx] = ox + fx;
    out[b*49152 + 16384 +  pidx] = oy + fy;
    out[b*49152 + 32768 +  pidx] = oz + fz;
    out[786432  + b*16384 + pidx] = rg_;
  }
}

extern "C" void kernel_launch(void* const* d_in, const int* in_sizes, int n_in,
                              void* d_out, int out_size, void* d_ws, size_t ws_size,
                              hipStream_t stream){
  const float* x     = (const float*)d_in[0];
  const float* dens  = (const float*)d_in[1];
  const float* noise = (const float*)d_in[2];
  const float* W1    = (const float*)d_in[3];
  const float* b1    = (const float*)d_in[4];
  const float* W2    = (const float*)d_in[5];
  const float* b2    = (const float*)d_in[6];
  const float* W3    = (const float*)d_in[7];
  const float* b3    = (const float*)d_in[8];

  char* ws = (char*)d_ws;
  int*      pc   = (int*)(ws + 0);
  _Float16* w1f  = (_Float16*)(ws + OFF_W1F);
  _Float16* w2f  = (_Float16*)(ws + OFF_W2F);
  _Float16* w3f  = (_Float16*)(ws + OFF_W3F);
  _Float16* xT   = (_Float16*)(ws + OFF_XT);
  float*    out  = (float*)d_out;

  const bool use_xt = (ws_size >= (size_t)WS_NEED);
  const int  nprep  = use_xt ? 318 : 62;

  kP<<<dim3(nprep), dim3(256), 0, stream>>>(dens, pc, W1, W2, W3, x,
                                            w1f, w2f, w3f, xT);
  if (use_xt)
    kE<true ><<<dim3(256, 16), dim3(256), 0, stream>>>(x, xT, noise, w1f, w2f, w3f,
                                                       b1, b2, b3, pc, out);
  else
    kE<false><<<dim3(256, 16), dim3(256), 0, stream>>>(x, xT, noise, w1f, w2f, w3f,
                                                       b1, b2, b3, pc, out);
}